// Round 4
// baseline (575.597 us; speedup 1.0000x reference)
//
#include <hip/hip_runtime.h>
#include <hip/hip_bf16.h>

#define NLIG 1024
#define NREC 4096
#define NTOT 5120
#define ELIG 8192
#define ETOT 40960
#define TCOLS 1088        // 17 slots * 64 (slot 16 = efb bias slot)
#define NBLK 384
#define NTHR 256
#define NWAVES (NBLK*4)       // 1536
#define NTHREADS (NBLK*NTHR)  // 98304

typedef __bf16 bf16x8 __attribute__((ext_vector_type(8)));
typedef float f32x4 __attribute__((ext_vector_type(4)));

struct Params {
  const float *lig_x, *rec_x, *lig_e, *rec_e;
  const int *lig_src, *lig_dst, *rec_src, *rec_dst;
  const float *nW[2], *nb[2], *eW[2], *eb[2], *hW[2], *hb[2], *g0[2], *b0[2];
  const float *efW[2], *efb[2], *convb[2], *outW[2], *outb[2], *lng[2], *lnb[2];
  int *bar, *deg;
  float *h, *prev0, *agg, *eh;
  __bf16 *T, *Abf, *Wp;
  float *out;
};

__device__ __forceinline__ float lrelu(float v){ return v > 0.f ? v : 0.01f * v; }

__device__ __forceinline__ float wsum(float v){
  #pragma unroll
  for (int off = 32; off > 0; off >>= 1) v += __shfl_xor(v, off, 64);
  return v;
}

// Grid barrier across NBLK co-resident blocks. RELEASE arrival flushes this
// XCD's L2 (dirty data -> coherence point); relaxed agent-scope spin sees
// remote arrivals; __threadfence() after = acquire (invalidates L1/L2) so
// post-barrier loads observe other XCDs' pre-barrier stores.
__device__ __forceinline__ void gbar(int* bar, int idx){
  __syncthreads();
  if (threadIdx.x == 0){
    __hip_atomic_fetch_add(&bar[idx*16], 1, __ATOMIC_RELEASE, __HIP_MEMORY_SCOPE_AGENT);
    while (__hip_atomic_load(&bar[idx*16], __ATOMIC_RELAXED, __HIP_MEMORY_SCOPE_AGENT) < NBLK)
      __builtin_amdgcn_s_sleep(1);
    __threadfence();
  }
  __syncthreads();
}

union Smem {
  struct { float sW[2][256], sb[2][16], sx[4][40], st[4][64]; } p0;
  struct { float sa[4][64]; } up;
  struct { float sl[64][65], sr[16][65], ps[4]; } sc;
};

__global__ __launch_bounds__(256, 2) void k_fused(Params p){
  __shared__ Smem sm;
  const int tid  = threadIdx.x, bid = blockIdx.x;
  const int lane = tid & 63,    wid = tid >> 6;
  const int gwave = bid*4 + wid;
  const int gtid  = bid*NTHR + tid;

  // ================= phase 0: prepW + edge emb + node emb + zeroing =========
  sm.p0.sW[0][tid] = p.eW[0][tid];
  sm.p0.sW[1][tid] = p.eW[1][tid];
  if (tid < 16){ sm.p0.sb[0][tid] = p.eb[0][tid]; sm.p0.sb[1][tid] = p.eb[1][tid]; }
  __syncthreads();

  // --- pack W_all = [efW 0..15 | efb] into MFMA B-fragment order ---
  if (gtid < 52224){
    int l  = gtid & 63;
    int t2 = gtid >> 6;
    int kk = t2 & 1;
    int t3 = t2 >> 1;
    int ct = t3 % 68;
    int sl = t3 / 68;            // side*3 + layer
    int side = sl / 3, layer = sl % 3;
    int ocol = ct*16 + (l & 15);
    int kslot = ocol >> 6, oo = ocol & 63;
    const float* src = (kslot < 16)
        ? (p.efW[side] + (size_t)layer*16*4096 + (size_t)kslot*4096)
        : (p.efb[side] + (size_t)layer*4096);
    bf16x8 w;
    #pragma unroll
    for (int j = 0; j < 8; j++){
      int i = kk*32 + (l >> 4)*8 + j;
      w[j] = (__bf16)src[i*64 + oo];
    }
    ((bf16x8*)p.Wp)[(size_t)sl*68*2*64 + (ct*2 + kk)*64 + l] = w;
  }

  // --- edge embedding + in-degree ---
  if (gtid < ETOT){
    int e = gtid;
    int side = e >= ELIG;
    int el = side ? e - ELIG : e;
    const float* ex = (side ? p.rec_e : p.lig_e) + (size_t)el * 16;
    float x[16];
    #pragma unroll
    for (int j = 0; j < 16; j += 4){
      float4 v = *(const float4*)(ex + j);
      x[j] = v.x; x[j+1] = v.y; x[j+2] = v.z; x[j+3] = v.w;
    }
    float s[16];
    #pragma unroll
    for (int k = 0; k < 16; k++){
      float acc = sm.p0.sb[side][k];
      #pragma unroll
      for (int j = 0; j < 16; j++) acc += x[j] * sm.p0.sW[side][j*16 + k];
      s[k] = acc;
    }
    float* ehp = p.eh + (size_t)e * 16;
    #pragma unroll
    for (int k = 0; k < 16; k += 4)
      *(float4*)(ehp + k) = make_float4(s[k], s[k+1], s[k+2], s[k+3]);
    int gd = side ? NLIG + p.rec_dst[el] : p.lig_dst[el];
    atomicAdd(&p.deg[gd], 1);
  }

  // --- zero agg and out[0..15] ---
  for (int i = gtid; i < NTOT*64; i += NTHREADS) p.agg[i] = 0.f;
  if (gtid < 16) p.out[gtid] = 0.f;

  // --- node embedding + LN0 (wave-local; per-wave LDS slices) ---
  for (int n = gwave; n < NTOT; n += NWAVES){
    int side = n >= NLIG;
    int nl = side ? n - NLIG : n;
    int nin = side ? 40 : 32;
    const float* x = (side ? p.rec_x : p.lig_x) + (size_t)nl * nin;
    if (lane < nin) sm.p0.sx[wid][lane] = x[lane];
    float tv = p.nb[side][lane];
    const float* nw = p.nW[side];
    for (int j = 0; j < nin; j++) tv += sm.p0.sx[wid][j] * nw[j*64 + lane];
    sm.p0.st[wid][lane] = lrelu(tv);
    float hv = p.hb[side][lane];
    const float* hw = p.hW[side];
    #pragma unroll 8
    for (int j = 0; j < 64; j++) hv += sm.p0.st[wid][j] * hw[j*64 + lane];
    float m = wsum(hv) * (1.f/64.f);
    float d = hv - m;
    float v = wsum(d*d) * (1.f/64.f);
    float o = d * rsqrtf(v + 1e-5f) * p.g0[side][lane] + p.b0[side][lane];
    p.h[(size_t)n*64 + lane] = o;
    p.Abf[(size_t)n*64 + lane] = (__bf16)lrelu(o);
  }

  gbar(p.bar, 0);

  // ================= layer loop =============================================
  for (int layer = 0; layer < 3; layer++){
    // --- tmat (MFMA): T[n, ks*64+o] = sum_i Abf[n,i] * W_all[i, ...] ---
    for (int u = gwave; u < 5440; u += NWAVES){
      int band = u / 17, ks = u % 17;
      int side = band >= 64;
      int r0 = band * 16;
      const bf16x8* A = (const bf16x8*)(p.Abf + (size_t)(r0 + (lane & 15))*64 + (lane >> 4)*8);
      bf16x8 a0 = A[0];       // k 0..31 slice
      bf16x8 a1 = A[4];       // k 32..63 slice
      const bf16x8* Wb = (const bf16x8*)p.Wp + (size_t)(side*3 + layer)*68*2*64;
      int orow = (lane >> 4)*4;
      #pragma unroll
      for (int c = 0; c < 4; c++){
        int ct = ks*4 + c;
        bf16x8 b0 = Wb[(ct*2 + 0)*64 + lane];
        bf16x8 b1 = Wb[(ct*2 + 1)*64 + lane];
        f32x4 d = {0.f, 0.f, 0.f, 0.f};
        d = __builtin_amdgcn_mfma_f32_16x16x32_bf16(a0, b0, d, 0, 0, 0);
        d = __builtin_amdgcn_mfma_f32_16x16x32_bf16(a1, b1, d, 0, 0, 0);
        int col = ct*16 + (lane & 15);
        __bf16* Tp = p.T + (size_t)(r0 + orow)*TCOLS + col;
        Tp[0*TCOLS] = (__bf16)d[0];
        Tp[1*TCOLS] = (__bf16)d[1];
        Tp[2*TCOLS] = (__bf16)d[2];
        Tp[3*TCOLS] = (__bf16)d[3];
      }
    }
    gbar(p.bar, 1 + layer*3);

    // --- msg: per-edge, one wave per edge, two edges in flight for ILP ---
    {
      auto do_edge = [&](int e){
        int side = e >= ELIG;
        int el = side ? e - ELIG : e;
        int src = side ? NLIG + p.rec_src[el] : p.lig_src[el];
        int dst = side ? NLIG + p.rec_dst[el] : p.lig_dst[el];
        const __bf16* Trow = p.T + (size_t)src * TCOLS + lane;
        const float4* ehp = (const float4*)(p.eh + (size_t)e * 16);
        float4 v0 = ehp[0], v1 = ehp[1], v2 = ehp[2], v3 = ehp[3];
        float m = (float)Trow[16*64];
        m += v0.x*(float)Trow[0*64]  + v0.y*(float)Trow[1*64]  + v0.z*(float)Trow[2*64]  + v0.w*(float)Trow[3*64];
        m += v1.x*(float)Trow[4*64]  + v1.y*(float)Trow[5*64]  + v1.z*(float)Trow[6*64]  + v1.w*(float)Trow[7*64];
        m += v2.x*(float)Trow[8*64]  + v2.y*(float)Trow[9*64]  + v2.z*(float)Trow[10*64] + v2.w*(float)Trow[11*64];
        m += v3.x*(float)Trow[12*64] + v3.y*(float)Trow[13*64] + v3.z*(float)Trow[14*64] + v3.w*(float)Trow[15*64];
        atomicAdd(&p.agg[(size_t)dst*64 + lane], m);
      };
      for (int e = gwave; e < ETOT; e += 2*NWAVES){
        int e2 = e + NWAVES;
        do_edge(e);
        if (e2 < ETOT) do_edge(e2);
      }
    }
    gbar(p.bar, 2 + layer*3);

    // --- upd: /deg + convb, lrelu, @outW, LN, residual; re-zero agg ---
    for (int n = gwave; n < NTOT; n += NWAVES){
      int side = n >= NLIG;
      float a = p.agg[(size_t)n*64 + lane];
      p.agg[(size_t)n*64 + lane] = 0.f;
      float dg = fmaxf((float)p.deg[n], 1.f);
      a = lrelu(a / dg + p.convb[side][layer*64 + lane]);
      sm.up.sa[wid][lane] = a;
      float hv = p.outb[side][layer*64 + lane];
      const float* ow = p.outW[side] + (size_t)layer*4096;
      #pragma unroll 8
      for (int j = 0; j < 64; j++) hv += sm.up.sa[wid][j] * ow[j*64 + lane];
      float m = wsum(hv) * (1.f/64.f);
      float d = hv - m;
      float v = wsum(d*d) * (1.f/64.f);
      float o = d * rsqrtf(v + 1e-5f) * p.lng[side][layer*64 + lane] + p.lnb[side][layer*64 + lane];
      if (layer == 2) o += p.prev0[(size_t)n*64 + lane];
      p.h[(size_t)n*64 + lane] = o;
      if (layer == 0) p.prev0[(size_t)n*64 + lane] = o;
      p.Abf[(size_t)n*64 + lane] = (__bf16)lrelu(o);
    }
    gbar(p.bar, 3 + layer*3);
  }

  // ================= score: op[b,l,r] = <lig_h, rec_h>; out[b] = mean =======
  if (bid < 256){
    int b = bid >> 4, rt = bid & 15;     // 16 batches x 16 rec-tiles of 16
    for (int idx = tid; idx < 4096; idx += NTHR){
      int r = idx >> 6, c = idx & 63;
      sm.sc.sl[r][c] = p.h[(size_t)(b*64 + r)*64 + c];
    }
    for (int idx = tid; idx < 1024; idx += NTHR){
      int r = idx >> 6, c = idx & 63;
      sm.sc.sr[r][c] = p.h[(size_t)(NLIG + b*256 + rt*16 + r)*64 + c];
    }
    __syncthreads();

    int r = tid & 15, lg = tid >> 4;     // rec col, lig 4-row group
    float acc0 = 0.f, acc1 = 0.f, acc2 = 0.f, acc3 = 0.f;
    #pragma unroll 8
    for (int f = 0; f < 64; f++){
      float bb = sm.sc.sr[r][f];
      acc0 += sm.sc.sl[lg*4+0][f] * bb;
      acc1 += sm.sc.sl[lg*4+1][f] * bb;
      acc2 += sm.sc.sl[lg*4+2][f] * bb;
      acc3 += sm.sc.sl[lg*4+3][f] * bb;
    }
    float* op = p.out + 16 + (size_t)b*16384 + (size_t)rt*16 + r;
    op[(size_t)(lg*4+0)*256] = acc0;
    op[(size_t)(lg*4+1)*256] = acc1;
    op[(size_t)(lg*4+2)*256] = acc2;
    op[(size_t)(lg*4+3)*256] = acc3;

    float psum = wsum(acc0 + acc1 + acc2 + acc3);
    if (lane == 0) sm.sc.ps[wid] = psum;
    __syncthreads();
    if (tid == 0)
      atomicAdd(&p.out[b], (sm.sc.ps[0]+sm.sc.ps[1]+sm.sc.ps[2]+sm.sc.ps[3]) * (1.f/16384.f));
  }
}

extern "C" void kernel_launch(void* const* d_in, const int* in_sizes, int n_in,
                              void* d_out, int out_size, void* d_ws, size_t ws_size,
                              hipStream_t stream){
  Params p;
  p.lig_x  = (const float*)d_in[0];
  p.rec_x  = (const float*)d_in[1];
  p.lig_e  = (const float*)d_in[2];
  p.rec_e  = (const float*)d_in[3];
  p.lig_src = (const int*)d_in[4];
  p.lig_dst = (const int*)d_in[5];
  p.rec_src = (const int*)d_in[6];
  p.rec_dst = (const int*)d_in[7];
  for (int s = 0; s < 2; s++){
    const int o = 8 + s*15;
    p.nW[s]   = (const float*)d_in[o+0];  p.nb[s]   = (const float*)d_in[o+1];
    p.eW[s]   = (const float*)d_in[o+2];  p.eb[s]   = (const float*)d_in[o+3];
    p.hW[s]   = (const float*)d_in[o+4];  p.hb[s]   = (const float*)d_in[o+5];
    p.g0[s]   = (const float*)d_in[o+6];  p.b0[s]   = (const float*)d_in[o+7];
    p.efW[s]  = (const float*)d_in[o+8];  p.efb[s]  = (const float*)d_in[o+9];
    p.convb[s]= (const float*)d_in[o+10]; p.outW[s] = (const float*)d_in[o+11];
    p.outb[s] = (const float*)d_in[o+12]; p.lng[s]  = (const float*)d_in[o+13];
    p.lnb[s]  = (const float*)d_in[o+14];
  }
  char* W = (char*)d_ws;
  p.bar   = (int*)W;    W += 256*4;                  // 16 barrier slots * 16-int stride
  p.deg   = (int*)W;    W += (size_t)NTOT*4;
  p.h     = (float*)W;  W += (size_t)NTOT*64*4;
  p.prev0 = (float*)W;  W += (size_t)NTOT*64*4;
  p.agg   = (float*)W;  W += (size_t)NTOT*64*4;
  p.eh    = (float*)W;  W += (size_t)ETOT*16*4;
  p.T     = (__bf16*)W; W += (size_t)NTOT*TCOLS*2;
  p.Abf   = (__bf16*)W; W += (size_t)NTOT*64*2;
  p.Wp    = (__bf16*)W; W += (size_t)2*3*68*2*64*8*2;
  p.out   = (float*)d_out;

  // zero barrier counters + deg in one shot
  hipMemsetAsync(p.bar, 0, (256 + NTOT)*sizeof(int), stream);
  k_fused<<<NBLK, NTHR, 0, stream>>>(p);
}

// Round 5
// 172.059 us; speedup vs baseline: 3.3453x; 3.3453x over previous
//
#include <hip/hip_runtime.h>
#include <hip/hip_bf16.h>

#define NLIG 1024
#define NREC 4096
#define NTOT 5120
#define ELIG 8192
#define ETOT 40960
#define TPAD 1092      // 17*64 padded +4: makes MFMA->LDS T writes bank-conflict-free

typedef __bf16 bf16x8 __attribute__((ext_vector_type(8)));
typedef float f32x4 __attribute__((ext_vector_type(4)));

struct Params {
  const float *lig_x, *rec_x, *lig_e, *rec_e;
  const int *lig_src, *lig_dst, *rec_src, *rec_dst;
  const float *nW[2], *nb[2], *eW[2], *eb[2], *hW[2], *hb[2], *g0[2], *b0[2];
  const float *efW[2], *efb[2], *convb[2], *outW[2], *outb[2], *lng[2], *lnb[2];
  float *aggA, *aggB, *prev0, *eh;
  __bf16 *Abf, *Wp;
  int *deg;
  float *out;
};

__device__ __forceinline__ float lrelu(float v){ return v > 0.f ? v : 0.01f * v; }

__device__ __forceinline__ float wsum(float v){
  #pragma unroll
  for (int off = 32; off > 0; off >>= 1) v += __shfl_xor(v, off, 64);
  return v;
}

// ---- K_pre: prepW + edge emb + node emb/LN0 -> Abf + zero agg/out ----------
__global__ __launch_bounds__(256) void k_pre(Params p){
  __shared__ float sW[2][256], sb[2][16], sx[4][40], st[4][64];
  const int tid = threadIdx.x, bid = blockIdx.x;
  const int lane = tid & 63, wid = tid >> 6;
  const int gtid = bid*256 + tid, gwave = bid*4 + wid;

  sW[0][tid] = p.eW[0][tid];
  sW[1][tid] = p.eW[1][tid];
  if (tid < 16){ sb[0][tid] = p.eb[0][tid]; sb[1][tid] = p.eb[1][tid]; }
  __syncthreads();

  // pack W_all = [efW 0..15 | efb] into MFMA B-fragment order
  if (gtid < 52224){
    int l  = gtid & 63;
    int t2 = gtid >> 6;
    int kk = t2 & 1;
    int t3 = t2 >> 1;
    int ct = t3 % 68;
    int sl = t3 / 68;            // side*3 + layer
    int side = sl / 3, layer = sl % 3;
    int ocol = ct*16 + (l & 15);
    int kslot = ocol >> 6, oo = ocol & 63;
    const float* src = (kslot < 16)
        ? (p.efW[side] + (size_t)layer*16*4096 + (size_t)kslot*4096)
        : (p.efb[side] + (size_t)layer*4096);
    bf16x8 w;
    #pragma unroll
    for (int j = 0; j < 8; j++){
      int i = kk*32 + (l >> 4)*8 + j;
      w[j] = (__bf16)src[i*64 + oo];
    }
    ((bf16x8*)p.Wp)[(size_t)sl*68*2*64 + (ct*2 + kk)*64 + l] = w;
  }

  // edge embedding
  if (gtid < ETOT){
    int e = gtid;
    int side = e >= ELIG;
    int el = side ? e - ELIG : e;
    const float* ex = (side ? p.rec_e : p.lig_e) + (size_t)el * 16;
    float x[16];
    #pragma unroll
    for (int j = 0; j < 16; j += 4){
      float4 v = *(const float4*)(ex + j);
      x[j] = v.x; x[j+1] = v.y; x[j+2] = v.z; x[j+3] = v.w;
    }
    float s[16];
    #pragma unroll
    for (int k = 0; k < 16; k++){
      float acc = sb[side][k];
      #pragma unroll
      for (int j = 0; j < 16; j++) acc += x[j] * sW[side][j*16 + k];
      s[k] = acc;
    }
    float* ehp = p.eh + (size_t)e * 16;
    #pragma unroll
    for (int k = 0; k < 16; k += 4)
      *(float4*)(ehp + k) = make_float4(s[k], s[k+1], s[k+2], s[k+3]);
  }

  // zero both agg buffers + out[0..15]
  for (int i = gtid; i < NTOT*64; i += 65536){ p.aggA[i] = 0.f; p.aggB[i] = 0.f; }
  if (gtid < 16) p.out[gtid] = 0.f;

  // node embedding + LN0 -> Abf (wave per node)
  for (int n = gwave; n < NTOT; n += 1024){
    int side = n >= NLIG;
    int nl = side ? n - NLIG : n;
    int nin = side ? 40 : 32;
    const float* x = (side ? p.rec_x : p.lig_x) + (size_t)nl * nin;
    if (lane < nin) sx[wid][lane] = x[lane];
    float tv = p.nb[side][lane];
    const float* nw = p.nW[side];
    for (int j = 0; j < nin; j++) tv += sx[wid][j] * nw[j*64 + lane];
    st[wid][lane] = lrelu(tv);
    float hv = p.hb[side][lane];
    const float* hw = p.hW[side];
    #pragma unroll 8
    for (int j = 0; j < 64; j++) hv += st[wid][j] * hw[j*64 + lane];
    float m = wsum(hv) * (1.f/64.f);
    float d = hv - m;
    float v = wsum(d*d) * (1.f/64.f);
    float o = d * rsqrtf(v + 1e-5f) * p.g0[side][lane] + p.b0[side][lane];
    p.Abf[(size_t)n*64 + lane] = (__bf16)lrelu(o);
  }
}

// ---- K_layer: [upd(layer-1) row-local] -> tmat (LDS T) -> bucketed msg ------
// 320 blocks: 64 lig (16 batches x 4 windows of 16 nodes), 256 rec (16 x 16).
__global__ __launch_bounds__(256) void k_layer(Params p, int layer){
  const int tid = threadIdx.x, bid = blockIdx.x;
  const int lane = tid & 63, wid = tid >> 6;
  int side, r0, gr0, ebase, ecnt, egbase;
  const int *srcArr, *dstArr;
  if (bid < 64){
    side = 0; int b = bid >> 2, w = bid & 3;
    r0 = b*64 + w*16; gr0 = r0; ebase = b*512; ecnt = 512; egbase = ebase;
    srcArr = p.lig_src; dstArr = p.lig_dst;
  } else {
    side = 1; int g = bid - 64; int b = g >> 4, w = g & 15;
    r0 = b*256 + w*16; gr0 = NLIG + r0; ebase = b*2048; ecnt = 2048; egbase = ELIG + ebase;
    srcArr = p.rec_src; dstArr = p.rec_dst;
  }
  float* aggR = (layer == 1) ? p.aggA : p.aggB;   // read by upd (layer-1)
  float* aggW = (layer == 1) ? p.aggB : p.aggA;   // written by msg (layer)

  __shared__ __bf16 Tl[16][TPAD];
  __shared__ __bf16 albf[16][64];
  __shared__ float sa[4][64];
  __shared__ unsigned short elist[2048];
  __shared__ int scnt[16], sbase[16], scur[16], dcnt[16];

  if (tid < 16){ scnt[tid] = 0; dcnt[tid] = 0; }
  __syncthreads();

  // pass 1: count out-edges per owned src (+ in-degree at layer 0)
  for (int i = tid; i < ecnt; i += 256){
    int s = srcArr[ebase + i];
    if ((unsigned)(s - r0) < 16u) atomicAdd(&scnt[s - r0], 1);
    if (layer == 0){
      int d = dstArr[ebase + i];
      if ((unsigned)(d - r0) < 16u) atomicAdd(&dcnt[d - r0], 1);
    }
  }
  __syncthreads();
  if (tid == 0){
    int acc = 0;
    for (int i = 0; i < 16; i++){ sbase[i] = acc; scur[i] = acc; acc += scnt[i]; }
  }
  if (layer == 0 && tid < 16) p.deg[gr0 + tid] = dcnt[tid];
  __syncthreads();
  // pass 2: scatter local edge ids into per-src buckets
  for (int i = tid; i < ecnt; i += 256){
    int s = srcArr[ebase + i];
    if ((unsigned)(s - r0) < 16u){
      int pos = atomicAdd(&scur[s - r0], 1);
      elist[pos] = (unsigned short)i;
    }
  }

  // upd(layer-1) for my 16 rows -> albf (A for tmat); ping-pong agg re-zero
  if (layer > 0){
    int lm1 = layer - 1;
    for (int rl = wid; rl < 16; rl += 4){
      int n = gr0 + rl;
      float a = aggR[(size_t)n*64 + lane];
      aggR[(size_t)n*64 + lane] = 0.f;
      float dg = fmaxf((float)p.deg[n], 1.f);
      a = lrelu(a / dg + p.convb[side][lm1*64 + lane]);
      sa[wid][lane] = a;
      float hv = p.outb[side][lm1*64 + lane];
      const float* ow = p.outW[side] + (size_t)lm1*4096;
      #pragma unroll 8
      for (int j = 0; j < 64; j++) hv += sa[wid][j] * ow[j*64 + lane];
      float m = wsum(hv) * (1.f/64.f);
      float d = hv - m;
      float v = wsum(d*d) * (1.f/64.f);
      float o = d * rsqrtf(v + 1e-5f) * p.lng[side][lm1*64 + lane] + p.lnb[side][lm1*64 + lane];
      if (layer == 1) p.prev0[(size_t)n*64 + lane] = o;   // h after layer 0 (residual)
      albf[rl][lane] = (__bf16)lrelu(o);
    }
  }
  __syncthreads();

  // tmat: T[16 rows][1088] = lrelu(h) @ W_all, straight into LDS
  bf16x8 a0, a1;
  if (layer == 0){
    const bf16x8* A = (const bf16x8*)(p.Abf + (size_t)(gr0 + (lane & 15))*64 + (lane >> 4)*8);
    a0 = A[0]; a1 = A[4];
  } else {
    #pragma unroll
    for (int j = 0; j < 8; j++){
      a0[j] = albf[lane & 15][(lane >> 4)*8 + j];
      a1[j] = albf[lane & 15][32 + (lane >> 4)*8 + j];
    }
  }
  const bf16x8* Wb = (const bf16x8*)p.Wp + (size_t)(side*3 + layer)*68*2*64;
  int orow = (lane >> 4)*4, ocol = lane & 15;
  for (int ct = wid; ct < 68; ct += 4){
    bf16x8 b0 = Wb[(ct*2 + 0)*64 + lane];
    bf16x8 b1 = Wb[(ct*2 + 1)*64 + lane];
    f32x4 d = {0.f, 0.f, 0.f, 0.f};
    d = __builtin_amdgcn_mfma_f32_16x16x32_bf16(a0, b0, d, 0, 0, 0);
    d = __builtin_amdgcn_mfma_f32_16x16x32_bf16(a1, b1, d, 0, 0, 0);
    int col = ct*16 + ocol;
    Tl[orow+0][col] = (__bf16)d[0];
    Tl[orow+1][col] = (__bf16)d[1];
    Tl[orow+2][col] = (__bf16)d[2];
    Tl[orow+3][col] = (__bf16)d[3];
  }
  __syncthreads();

  // msg: per owned src, load T row once to regs, stream its out-edges
  for (int s = wid; s < 16; s += 4){
    int cnt = scnt[s];
    if (cnt == 0) continue;
    float t[17];
    #pragma unroll
    for (int k = 0; k < 17; k++) t[k] = (float)Tl[s][k*64 + lane];
    int base = sbase[s];
    auto doe = [&](int idx){
      int leid = elist[base + idx];
      int gd = dstArr[ebase + leid];
      if (side) gd += NLIG;
      const float4* ehp = (const float4*)(p.eh + (size_t)(egbase + leid)*16);
      float4 v0 = ehp[0], v1 = ehp[1], v2 = ehp[2], v3 = ehp[3];
      float m = t[16];
      m += v0.x*t[0]  + v0.y*t[1]  + v0.z*t[2]  + v0.w*t[3];
      m += v1.x*t[4]  + v1.y*t[5]  + v1.z*t[6]  + v1.w*t[7];
      m += v2.x*t[8]  + v2.y*t[9]  + v2.z*t[10] + v2.w*t[11];
      m += v3.x*t[12] + v3.y*t[13] + v3.z*t[14] + v3.w*t[15];
      atomicAdd(&aggW[(size_t)gd*64 + lane], m);
    };
    int i = 0;
    for (; i + 2 <= cnt; i += 2){ doe(i); doe(i+1); }
    if (i < cnt) doe(i);
  }
}

// ---- K_final: upd(2) into LDS (lig rows recomputed per block) + score -------
__global__ __launch_bounds__(256) void k_final(Params p){
  const int tid = threadIdx.x, bid = blockIdx.x;
  const int lane = tid & 63, wid = tid >> 6;
  int b = bid >> 4, rt = bid & 15;
  __shared__ float slh[64][65];
  __shared__ float srh[16][65];
  __shared__ float owl[2][4096];
  __shared__ float sa[4][64];
  __shared__ float ps[4];

  for (int idx = tid; idx < 4096; idx += 256){
    owl[0][idx] = p.outW[0][2*4096 + idx];
    owl[1][idx] = p.outW[1][2*4096 + idx];
  }
  __syncthreads();

  // upd_2 for 64 lig rows of batch b + my 16 rec rows
  for (int rr = wid; rr < 80; rr += 4){
    int side = rr >= 64;
    int n = side ? (NLIG + b*256 + rt*16 + (rr - 64)) : (b*64 + rr);
    float a = p.aggA[(size_t)n*64 + lane];
    float dg = fmaxf((float)p.deg[n], 1.f);
    a = lrelu(a / dg + p.convb[side][128 + lane]);
    sa[wid][lane] = a;
    float hv = p.outb[side][128 + lane];
    const float* ow = &owl[side][0];
    #pragma unroll 8
    for (int j = 0; j < 64; j++) hv += sa[wid][j] * ow[j*64 + lane];
    float m = wsum(hv) * (1.f/64.f);
    float d = hv - m;
    float v = wsum(d*d) * (1.f/64.f);
    float o = d * rsqrtf(v + 1e-5f) * p.lng[side][128 + lane] + p.lnb[side][128 + lane];
    o += p.prev0[(size_t)n*64 + lane];     // residual: + h after layer 0
    if (side) srh[rr - 64][lane] = o; else slh[rr][lane] = o;
  }
  __syncthreads();

  // score: op[b, l, rt*16 + r] = <lig_h[l], rec_h[r]>
  int r = tid & 15, lg = tid >> 4;
  float acc0 = 0.f, acc1 = 0.f, acc2 = 0.f, acc3 = 0.f;
  #pragma unroll 8
  for (int f = 0; f < 64; f++){
    float bb = srh[r][f];
    acc0 += slh[lg*4+0][f] * bb;
    acc1 += slh[lg*4+1][f] * bb;
    acc2 += slh[lg*4+2][f] * bb;
    acc3 += slh[lg*4+3][f] * bb;
  }
  float* op = p.out + 16 + (size_t)b*16384 + (size_t)rt*16 + r;
  op[(size_t)(lg*4+0)*256] = acc0;
  op[(size_t)(lg*4+1)*256] = acc1;
  op[(size_t)(lg*4+2)*256] = acc2;
  op[(size_t)(lg*4+3)*256] = acc3;

  float psum = wsum(acc0 + acc1 + acc2 + acc3);
  if (lane == 0) ps[wid] = psum;
  __syncthreads();
  if (tid == 0)
    atomicAdd(&p.out[b], (ps[0]+ps[1]+ps[2]+ps[3]) * (1.f/16384.f));
}

extern "C" void kernel_launch(void* const* d_in, const int* in_sizes, int n_in,
                              void* d_out, int out_size, void* d_ws, size_t ws_size,
                              hipStream_t stream){
  Params p;
  p.lig_x  = (const float*)d_in[0];
  p.rec_x  = (const float*)d_in[1];
  p.lig_e  = (const float*)d_in[2];
  p.rec_e  = (const float*)d_in[3];
  p.lig_src = (const int*)d_in[4];
  p.lig_dst = (const int*)d_in[5];
  p.rec_src = (const int*)d_in[6];
  p.rec_dst = (const int*)d_in[7];
  for (int s = 0; s < 2; s++){
    const int o = 8 + s*15;
    p.nW[s]   = (const float*)d_in[o+0];  p.nb[s]   = (const float*)d_in[o+1];
    p.eW[s]   = (const float*)d_in[o+2];  p.eb[s]   = (const float*)d_in[o+3];
    p.hW[s]   = (const float*)d_in[o+4];  p.hb[s]   = (const float*)d_in[o+5];
    p.g0[s]   = (const float*)d_in[o+6];  p.b0[s]   = (const float*)d_in[o+7];
    p.efW[s]  = (const float*)d_in[o+8];  p.efb[s]  = (const float*)d_in[o+9];
    p.convb[s]= (const float*)d_in[o+10]; p.outW[s] = (const float*)d_in[o+11];
    p.outb[s] = (const float*)d_in[o+12]; p.lng[s]  = (const float*)d_in[o+13];
    p.lnb[s]  = (const float*)d_in[o+14];
  }
  char* W = (char*)d_ws;
  p.aggA  = (float*)W;  W += (size_t)NTOT*64*4;
  p.aggB  = (float*)W;  W += (size_t)NTOT*64*4;
  p.prev0 = (float*)W;  W += (size_t)NTOT*64*4;
  p.eh    = (float*)W;  W += (size_t)ETOT*16*4;
  p.Abf   = (__bf16*)W; W += (size_t)NTOT*64*2;
  p.Wp    = (__bf16*)W; W += (size_t)2*3*68*2*64*8*2;
  p.deg   = (int*)W;    W += (size_t)NTOT*4;
  p.out   = (float*)d_out;

  k_pre<<<256, 256, 0, stream>>>(p);
  k_layer<<<320, 256, 0, stream>>>(p, 0);
  k_layer<<<320, 256, 0, stream>>>(p, 1);
  k_layer<<<320, 256, 0, stream>>>(p, 2);
  k_final<<<256, 256, 0, stream>>>(p);
}

// Round 6
// 116.263 us; speedup vs baseline: 4.9508x; 1.4799x over previous
//
#include <hip/hip_runtime.h>
#include <hip/hip_bf16.h>

#define NLIG 1024
#define NREC 4096
#define NTOT 5120
#define ELIG 8192
#define ETOT 40960
#define TPAD 1092      // 17*64 padded +4

typedef __bf16 bf16x8 __attribute__((ext_vector_type(8)));
typedef float f32x4 __attribute__((ext_vector_type(4)));

struct Params {
  const float *lig_x, *rec_x, *lig_e, *rec_e;
  const int *lig_src, *lig_dst, *rec_src, *rec_dst;
  const float *nW[2], *nb[2], *eW[2], *eb[2], *hW[2], *hb[2], *g0[2], *b0[2];
  const float *efW[2], *efb[2], *convb[2], *outW[2], *outb[2], *lng[2], *lnb[2];
  float *aggA, *aggB, *prev0, *eh;
  __bf16 *Abf, *Wp;
  int *deg;
  float *out;
};

__device__ __forceinline__ float lrelu(float v){ return v > 0.f ? v : 0.01f * v; }

__device__ __forceinline__ float wsum(float v){
  #pragma unroll
  for (int off = 32; off > 0; off >>= 1) v += __shfl_xor(v, off, 64);
  return v;
}

// ---- K_pre: prepW + edge emb + node emb/LN0 -> Abf + zero agg/out ----------
__global__ __launch_bounds__(256) void k_pre(Params p){
  __shared__ float sW[2][256], sb[2][16], sx[4][40], st[4][64];
  const int tid = threadIdx.x, bid = blockIdx.x;
  const int lane = tid & 63, wid = tid >> 6;
  const int gtid = bid*256 + tid, gwave = bid*4 + wid;

  sW[0][tid] = p.eW[0][tid];
  sW[1][tid] = p.eW[1][tid];
  if (tid < 16){ sb[0][tid] = p.eb[0][tid]; sb[1][tid] = p.eb[1][tid]; }
  __syncthreads();

  // pack W_all = [efW 0..15 | efb] into MFMA B-fragment order
  if (gtid < 52224){
    int l  = gtid & 63;
    int t2 = gtid >> 6;
    int kk = t2 & 1;
    int t3 = t2 >> 1;
    int ct = t3 % 68;
    int sl = t3 / 68;            // side*3 + layer
    int side = sl / 3, layer = sl % 3;
    int ocol = ct*16 + (l & 15);
    int kslot = ocol >> 6, oo = ocol & 63;
    const float* src = (kslot < 16)
        ? (p.efW[side] + (size_t)layer*16*4096 + (size_t)kslot*4096)
        : (p.efb[side] + (size_t)layer*4096);
    bf16x8 w;
    #pragma unroll
    for (int j = 0; j < 8; j++){
      int i = kk*32 + (l >> 4)*8 + j;
      w[j] = (__bf16)src[i*64 + oo];
    }
    ((bf16x8*)p.Wp)[(size_t)sl*68*2*64 + (ct*2 + kk)*64 + l] = w;
  }

  // edge embedding
  if (gtid < ETOT){
    int e = gtid;
    int side = e >= ELIG;
    int el = side ? e - ELIG : e;
    const float* ex = (side ? p.rec_e : p.lig_e) + (size_t)el * 16;
    float x[16];
    #pragma unroll
    for (int j = 0; j < 16; j += 4){
      float4 v = *(const float4*)(ex + j);
      x[j] = v.x; x[j+1] = v.y; x[j+2] = v.z; x[j+3] = v.w;
    }
    float s[16];
    #pragma unroll
    for (int k = 0; k < 16; k++){
      float acc = sb[side][k];
      #pragma unroll
      for (int j = 0; j < 16; j++) acc += x[j] * sW[side][j*16 + k];
      s[k] = acc;
    }
    float* ehp = p.eh + (size_t)e * 16;
    #pragma unroll
    for (int k = 0; k < 16; k += 4)
      *(float4*)(ehp + k) = make_float4(s[k], s[k+1], s[k+2], s[k+3]);
  }

  // zero both agg buffers + out[0..15]
  for (int i = gtid; i < NTOT*64; i += 65536){ p.aggA[i] = 0.f; p.aggB[i] = 0.f; }
  if (gtid < 16) p.out[gtid] = 0.f;

  // node embedding + LN0 -> Abf (wave per node)
  for (int n = gwave; n < NTOT; n += 1024){
    int side = n >= NLIG;
    int nl = side ? n - NLIG : n;
    int nin = side ? 40 : 32;
    const float* x = (side ? p.rec_x : p.lig_x) + (size_t)nl * nin;
    if (lane < nin) sx[wid][lane] = x[lane];
    float tv = p.nb[side][lane];
    const float* nw = p.nW[side];
    for (int j = 0; j < nin; j++) tv += sx[wid][j] * nw[j*64 + lane];
    st[wid][lane] = lrelu(tv);
    float hv = p.hb[side][lane];
    const float* hw = p.hW[side];
    #pragma unroll 8
    for (int j = 0; j < 64; j++) hv += st[wid][j] * hw[j*64 + lane];
    float m = wsum(hv) * (1.f/64.f);
    float d = hv - m;
    float v = wsum(d*d) * (1.f/64.f);
    float o = d * rsqrtf(v + 1e-5f) * p.g0[side][lane] + p.b0[side][lane];
    p.Abf[(size_t)n*64 + lane] = (__bf16)lrelu(o);
  }
}

// ---- K_layer: [upd(layer-1)] -> tmat (LDS T) -> bucketed msg ----------------
// 320 blocks x 1024 threads (16 waves). Block owns 16 nodes of one graph.
__global__ __launch_bounds__(1024) void k_layer(Params p, int layer){
  const int tid = threadIdx.x, bid = blockIdx.x;
  const int lane = tid & 63, wid = tid >> 6;        // wid 0..15
  int side, r0, gr0, ebase, ecnt, egbase;
  const int *srcArr, *dstArr;
  if (bid < 64){
    side = 0; int b = bid >> 2, w = bid & 3;
    r0 = b*64 + w*16; gr0 = r0; ebase = b*512; ecnt = 512; egbase = ebase;
    srcArr = p.lig_src; dstArr = p.lig_dst;
  } else {
    side = 1; int g = bid - 64; int b = g >> 4, w = g & 15;
    r0 = b*256 + w*16; gr0 = NLIG + r0; ebase = b*2048; ecnt = 2048; egbase = ELIG + ebase;
    srcArr = p.rec_src; dstArr = p.rec_dst;
  }
  float* aggR = (layer == 1) ? p.aggA : p.aggB;   // read by upd (layer-1)
  float* aggW = (layer == 1) ? p.aggB : p.aggA;   // written by msg (layer)

  __shared__ __bf16 Tl[16][TPAD];          // 34.9 KB
  __shared__ __bf16 albf[16][64];          // 2 KB
  __shared__ float sa[16][64];             // 4 KB
  __shared__ unsigned int elist[2048];     // 8 KB: (dst<<16)|local_eid
  __shared__ int scnt[16], sbase[16], scur[16], dcnt[16];

  if (tid < 16){ scnt[tid] = 0; dcnt[tid] = 0; }
  __syncthreads();

  // pass 1: count out-edges per owned src (+ in-degree at layer 0)
  for (int i = tid; i < ecnt; i += 1024){
    int s = srcArr[ebase + i];
    if ((unsigned)(s - r0) < 16u) atomicAdd(&scnt[s - r0], 1);
    if (layer == 0){
      int d = dstArr[ebase + i];
      if ((unsigned)(d - r0) < 16u) atomicAdd(&dcnt[d - r0], 1);
    }
  }
  __syncthreads();
  // prefix scan over 16 bucket counts (wave 0)
  if (tid < 64){
    int v = (lane < 16) ? scnt[lane] : 0;
    int pre = v;
    #pragma unroll
    for (int off = 1; off < 16; off <<= 1){
      int u = __shfl_up(pre, off, 64);
      if (lane >= off) pre += u;
    }
    if (lane < 16){ sbase[lane] = pre - v; scur[lane] = pre - v; }
  }
  if (layer == 0 && tid < 16) p.deg[gr0 + tid] = dcnt[tid];
  __syncthreads();
  // pass 2: scatter (dst | eid) into per-src buckets
  for (int i = tid; i < ecnt; i += 1024){
    int s = srcArr[ebase + i];
    if ((unsigned)(s - r0) < 16u){
      int d = dstArr[ebase + i];
      int pos = atomicAdd(&scur[s - r0], 1);
      elist[pos] = ((unsigned)d << 16) | (unsigned)i;
    }
  }

  // upd(layer-1) for my row (one row per wave) -> albf; ping-pong agg re-zero
  if (layer > 0){
    int lm1 = layer - 1;
    int rl = wid;
    int n = gr0 + rl;
    float a = aggR[(size_t)n*64 + lane];
    aggR[(size_t)n*64 + lane] = 0.f;
    float dg = fmaxf((float)p.deg[n], 1.f);
    a = lrelu(a / dg + p.convb[side][lm1*64 + lane]);
    sa[wid][lane] = a;
    float hv = p.outb[side][lm1*64 + lane];
    const float* ow = p.outW[side] + (size_t)lm1*4096;
    #pragma unroll 8
    for (int j = 0; j < 64; j++) hv += sa[wid][j] * ow[j*64 + lane];
    float m = wsum(hv) * (1.f/64.f);
    float d = hv - m;
    float v = wsum(d*d) * (1.f/64.f);
    float o = d * rsqrtf(v + 1e-5f) * p.lng[side][lm1*64 + lane] + p.lnb[side][lm1*64 + lane];
    if (layer == 1) p.prev0[(size_t)n*64 + lane] = o;   // h after layer 0 (residual)
    albf[rl][lane] = (__bf16)lrelu(o);
  }
  __syncthreads();

  // tmat: T[16 rows][1088] = lrelu(h) @ W_all, straight into LDS
  bf16x8 a0, a1;
  if (layer == 0){
    const bf16x8* A = (const bf16x8*)(p.Abf + (size_t)(gr0 + (lane & 15))*64 + (lane >> 4)*8);
    a0 = A[0]; a1 = A[4];
  } else {
    #pragma unroll
    for (int j = 0; j < 8; j++){
      a0[j] = albf[lane & 15][(lane >> 4)*8 + j];
      a1[j] = albf[lane & 15][32 + (lane >> 4)*8 + j];
    }
  }
  const bf16x8* Wb = (const bf16x8*)p.Wp + (size_t)(side*3 + layer)*68*2*64;
  int orow = (lane >> 4)*4, ocol = lane & 15;
  for (int ct = wid; ct < 68; ct += 16){
    bf16x8 b0 = Wb[(ct*2 + 0)*64 + lane];
    bf16x8 b1 = Wb[(ct*2 + 1)*64 + lane];
    f32x4 d = {0.f, 0.f, 0.f, 0.f};
    d = __builtin_amdgcn_mfma_f32_16x16x32_bf16(a0, b0, d, 0, 0, 0);
    d = __builtin_amdgcn_mfma_f32_16x16x32_bf16(a1, b1, d, 0, 0, 0);
    int col = ct*16 + ocol;
    Tl[orow+0][col] = (__bf16)d[0];
    Tl[orow+1][col] = (__bf16)d[1];
    Tl[orow+2][col] = (__bf16)d[2];
    Tl[orow+3][col] = (__bf16)d[3];
  }
  __syncthreads();

  // msg: one src per wave; T row in regs; stream its out-edges (ILP 2)
  {
    int s = wid;
    int cnt = scnt[s];
    if (cnt > 0){
      float t[17];
      #pragma unroll
      for (int k = 0; k < 17; k++) t[k] = (float)Tl[s][k*64 + lane];
      int base = sbase[s];
      auto doe = [&](int idx){
        unsigned v = elist[base + idx];
        int gd = (int)(v >> 16) + (side ? NLIG : 0);
        int leid = (int)(v & 0xffffu);
        const float4* ehp = (const float4*)(p.eh + (size_t)(egbase + leid)*16);
        float4 v0 = ehp[0], v1 = ehp[1], v2 = ehp[2], v3 = ehp[3];
        float m = t[16];
        m += v0.x*t[0]  + v0.y*t[1]  + v0.z*t[2]  + v0.w*t[3];
        m += v1.x*t[4]  + v1.y*t[5]  + v1.z*t[6]  + v1.w*t[7];
        m += v2.x*t[8]  + v2.y*t[9]  + v2.z*t[10] + v2.w*t[11];
        m += v3.x*t[12] + v3.y*t[13] + v3.z*t[14] + v3.w*t[15];
        atomicAdd(&aggW[(size_t)gd*64 + lane], m);
      };
      int i = 0;
      for (; i + 2 <= cnt; i += 2){ doe(i); doe(i+1); }
      if (i < cnt) doe(i);
    }
  }
}

// ---- K_final: upd(2) into LDS + score (1024 threads) ------------------------
__global__ __launch_bounds__(1024) void k_final(Params p){
  const int tid = threadIdx.x, bid = blockIdx.x;
  const int lane = tid & 63, wid = tid >> 6;       // wid 0..15
  int b = bid >> 4, rt = bid & 15;
  __shared__ float slh[64][65];
  __shared__ float srh[16][65];
  __shared__ float owl[2][4096];
  __shared__ float sa[16][64];
  __shared__ float ps[16];

  for (int idx = tid; idx < 4096; idx += 1024){
    owl[0][idx] = p.outW[0][2*4096 + idx];
    owl[1][idx] = p.outW[1][2*4096 + idx];
  }
  __syncthreads();

  // upd_2 for 64 lig rows of batch b + my 16 rec rows (5 rows per wave)
  for (int rr = wid; rr < 80; rr += 16){
    int side = rr >= 64;
    int n = side ? (NLIG + b*256 + rt*16 + (rr - 64)) : (b*64 + rr);
    float a = p.aggA[(size_t)n*64 + lane];
    float dg = fmaxf((float)p.deg[n], 1.f);
    a = lrelu(a / dg + p.convb[side][128 + lane]);
    sa[wid][lane] = a;
    float hv = p.outb[side][128 + lane];
    const float* ow = &owl[side][0];
    #pragma unroll 8
    for (int j = 0; j < 64; j++) hv += sa[wid][j] * ow[j*64 + lane];
    float m = wsum(hv) * (1.f/64.f);
    float d = hv - m;
    float v = wsum(d*d) * (1.f/64.f);
    float o = d * rsqrtf(v + 1e-5f) * p.lng[side][128 + lane] + p.lnb[side][128 + lane];
    o += p.prev0[(size_t)n*64 + lane];     // residual: + h after layer 0
    if (side) srh[rr - 64][lane] = o; else slh[rr][lane] = o;
  }
  __syncthreads();

  // score: each thread owns one (lig row, rec col) pair
  int r = tid & 15, lg = tid >> 4;         // r 0..15, lg 0..63
  float acc = 0.f;
  #pragma unroll 8
  for (int f = 0; f < 64; f++) acc += slh[lg][f] * srh[r][f];
  p.out[16 + (size_t)b*16384 + (size_t)lg*256 + rt*16 + r] = acc;

  float psum = wsum(acc);
  if (lane == 0) ps[wid] = psum;
  __syncthreads();
  if (tid == 0){
    float s = 0.f;
    #pragma unroll
    for (int i = 0; i < 16; i++) s += ps[i];
    atomicAdd(&p.out[b], s * (1.f/16384.f));
  }
}

extern "C" void kernel_launch(void* const* d_in, const int* in_sizes, int n_in,
                              void* d_out, int out_size, void* d_ws, size_t ws_size,
                              hipStream_t stream){
  Params p;
  p.lig_x  = (const float*)d_in[0];
  p.rec_x  = (const float*)d_in[1];
  p.lig_e  = (const float*)d_in[2];
  p.rec_e  = (const float*)d_in[3];
  p.lig_src = (const int*)d_in[4];
  p.lig_dst = (const int*)d_in[5];
  p.rec_src = (const int*)d_in[6];
  p.rec_dst = (const int*)d_in[7];
  for (int s = 0; s < 2; s++){
    const int o = 8 + s*15;
    p.nW[s]   = (const float*)d_in[o+0];  p.nb[s]   = (const float*)d_in[o+1];
    p.eW[s]   = (const float*)d_in[o+2];  p.eb[s]   = (const float*)d_in[o+3];
    p.hW[s]   = (const float*)d_in[o+4];  p.hb[s]   = (const float*)d_in[o+5];
    p.g0[s]   = (const float*)d_in[o+6];  p.b0[s]   = (const float*)d_in[o+7];
    p.efW[s]  = (const float*)d_in[o+8];  p.efb[s]  = (const float*)d_in[o+9];
    p.convb[s]= (const float*)d_in[o+10]; p.outW[s] = (const float*)d_in[o+11];
    p.outb[s] = (const float*)d_in[o+12]; p.lng[s]  = (const float*)d_in[o+13];
    p.lnb[s]  = (const float*)d_in[o+14];
  }
  char* W = (char*)d_ws;
  p.aggA  = (float*)W;  W += (size_t)NTOT*64*4;
  p.aggB  = (float*)W;  W += (size_t)NTOT*64*4;
  p.prev0 = (float*)W;  W += (size_t)NTOT*64*4;
  p.eh    = (float*)W;  W += (size_t)ETOT*16*4;
  p.Abf   = (__bf16*)W; W += (size_t)NTOT*64*2;
  p.Wp    = (__bf16*)W; W += (size_t)2*3*68*2*64*8*2;
  p.deg   = (int*)W;    W += (size_t)NTOT*4;
  p.out   = (float*)d_out;

  k_pre<<<256, 256, 0, stream>>>(p);
  k_layer<<<320, 1024, 0, stream>>>(p, 0);
  k_layer<<<320, 1024, 0, stream>>>(p, 1);
  k_layer<<<320, 1024, 0, stream>>>(p, 2);
  k_final<<<256, 1024, 0, stream>>>(p);
}